// Round 7
// baseline (5203.249 us; speedup 1.0000x reference)
//
#include <hip/hip_runtime.h>

#define N 8192
#define MAX_ITER 128
#define EPS 1e-6f
#define TAU_I8 12.0f     // int8 screen band: quant sigma ~1.63 -> 7.3 sigma
#define TAU_R  0.05f     // residual tier band: sigma ~6.4e-3 -> 7.8 sigma
#define QINV   0.0625f   // 1/16
#define RINV   (1.0f/4096.0f)

__device__ __forceinline__ float sgnf(float v) {
    return (v > 0.f) ? 1.f : ((v < 0.f) ? -1.f : 0.f);
}

// ---------------------------------------------------------------------------
// init: zero eacc/done/satflag (ws re-poisoned 0xAA before every call)
// ---------------------------------------------------------------------------
__global__ __launch_bounds__(256) void init_kernel(float* __restrict__ eacc,
                                                   int* __restrict__ done,
                                                   int* __restrict__ satflag) {
    int i = blockIdx.x * 256 + threadIdx.x;
    if (i < N) satflag[i] = 0;
    if (i < MAX_ITER) eacc[i] = 0.f;
    if (i == 0) *done = 0;
}

// ---------------------------------------------------------------------------
// compress: W fp32 -> Wq int8 (scale 16) + Rq int8 residual (scale 4096).
// r = w - q/16 is exact in fp32 (same-binade subtraction). 16 elts/thread.
// q-saturation (never for N(0,1); max|w|*16 ~ 98 < 127) -> satflag row.
// ---------------------------------------------------------------------------
__global__ __launch_bounds__(256) void compress_kernel(const float* __restrict__ W,
                                                       signed char* __restrict__ Wq,
                                                       signed char* __restrict__ Rq,
                                                       int* __restrict__ satflag) {
    const size_t base = ((size_t)blockIdx.x * 256 + threadIdx.x) * 16;
    const float4* w4 = (const float4*)(W + base);
    int sat = 0;
    uint4 oq, orr;
    unsigned* pq = (unsigned*)&oq;
    unsigned* pr = (unsigned*)&orr;
    #pragma unroll
    for (int v = 0; v < 4; ++v) {
        float4 w = w4[v];
        unsigned uq = 0, ur = 0;
        const float* e = (const float*)&w;
        #pragma unroll
        for (int k = 0; k < 4; ++k) {
            int q = __float2int_rn(e[k] * 16.0f);
            if (q > 127)  { q = 127;  sat = 1; }
            if (q < -127) { q = -127; sat = 1; }
            float r = e[k] - (float)q * QINV;        // exact
            int rq = __float2int_rn(r * 4096.0f);
            if (rq > 127)  rq = 127;                  // |r|<=1/32 -> |rq|<=128 tie
            if (rq < -127) rq = -127;
            uq |= ((unsigned)(q & 0xff)) << (8 * k);
            ur |= ((unsigned)(rq & 0xff)) << (8 * k);
        }
        pq[v] = uq; pr[v] = ur;
    }
    *(uint4*)(Wq + base) = oq;
    *(uint4*)(Rq + base) = orr;
    if (sat) atomicOr(&satflag[base >> 13], 1);
}

// dot of one packed uint4 row-chunk against 4 plane float4s
#define ACC_CHUNK(w_, q0_, q1_, q2_, q3_, a0_, a1_, a2_, a3_)                   \
    a0_ += (float)(signed char)((w_).x & 0xff)         * (q0_).x                \
         + (float)(signed char)(((w_).x >> 8) & 0xff)  * (q0_).y                \
         + (float)(signed char)(((w_).x >> 16) & 0xff) * (q0_).z                \
         + (float)(signed char)((w_).x >> 24)          * (q0_).w;               \
    a1_ += (float)(signed char)((w_).y & 0xff)         * (q1_).x                \
         + (float)(signed char)(((w_).y >> 8) & 0xff)  * (q1_).y                \
         + (float)(signed char)(((w_).y >> 16) & 0xff) * (q1_).z                \
         + (float)(signed char)((w_).y >> 24)          * (q1_).w;               \
    a2_ += (float)(signed char)((w_).z & 0xff)         * (q2_).x                \
         + (float)(signed char)(((w_).z >> 8) & 0xff)  * (q2_).y                \
         + (float)(signed char)(((w_).z >> 16) & 0xff) * (q2_).z                \
         + (float)(signed char)((w_).z >> 24)          * (q2_).w;               \
    a3_ += (float)(signed char)((w_).w & 0xff)         * (q3_).x                \
         + (float)(signed char)(((w_).w >> 8) & 0xff)  * (q3_).y                \
         + (float)(signed char)(((w_).w >> 16) & 0xff) * (q3_).z                \
         + (float)(signed char)((w_).w >> 24)          * (q3_).w;

// ---------------------------------------------------------------------------
// step(t): the ONLY per-iteration kernel. 1024 blocks x 512 thr, 1 row/wave.
//   preload Wq row (8 uint4 -> VGPRs)
//   stage x_t = (t==0 ? x0 : sign(y_{t-1}+b)) into 4 padded LDS planes;
//     energy E_{t-1} via wave-shuffle (2 barriers); uniform convergence check
//   screen: tot_q = int-exact q-dot (butterfly -> all lanes)
//   |tot_q/16 + b| < TAU or sat -> residual refine (8KB Rq row);
//     |y2 + b| < TAU_R or sat -> bitwise-R3 fp32 recompute (32KB W row)
//   lane0 writes final y_t[row] (single write)
// ---------------------------------------------------------------------------
__global__ __launch_bounds__(512, 4)
void step_kernel(const signed char* __restrict__ Wq,
                 const signed char* __restrict__ Rq,
                 const float* __restrict__ W,
                 const float* __restrict__ bias,
                 const float* __restrict__ x0,
                 const float* __restrict__ yin,       // y_{t-1}
                 float* __restrict__ yout,            // y_t
                 const signed char* __restrict__ xprev,   // packed x_{t-1}
                 signed char* __restrict__ xout,          // packed x_t
                 float* __restrict__ eacc,
                 const int* __restrict__ satflag,
                 int t,
                 int* __restrict__ done) {
    if (*done) return;                       // uniform

    __shared__ float xsw[4 * 2052];          // 4 planes x 513 float4, pad kills conflicts
    __shared__ float esum[8];

    const int tid  = threadIdx.x;
    const int wave = tid >> 6;
    const int lane = tid & 63;
    const int row  = ((int)blockIdx.x << 3) + wave;

    // ---- preload int8 W row into VGPRs (HBM busy from cycle 0) ----
    const uint4* Wr = (const uint4*)(Wq + (size_t)row * N);
    uint4 wq[8];
    #pragma unroll
    for (int p = 0; p < 8; ++p) wq[p] = Wr[(p << 6) + lane];

    float4* xsw4 = (float4*)xsw;
    float epart = 0.f;

    if (t == 0) {
        const float4* x4 = (const float4*)x0;
        #pragma unroll
        for (int k = 0; k < 4; ++k) {
            int i = tid + (k << 9);
            xsw4[(i & 3) * 513 + (i >> 2)] = x4[i];
        }
    } else {
        const float4* y4  = (const float4*)yin;
        const float4* b4  = (const float4*)bias;
        const char4*  xp4 = (const char4*)xprev;
        const float4* x04 = (const float4*)x0;
        const bool wr = (blockIdx.x == 0);
        #pragma unroll
        for (int k = 0; k < 4; ++k) {
            int i = tid + (k << 9);
            float4 y = y4[i];
            float4 b = b4[i];
            float4 xp;                        // x_{t-1} for energy
            if (t == 1) { xp = x04[i]; }
            else { char4 c = xp4[i]; xp = make_float4((float)c.x, (float)c.y,
                                                      (float)c.z, (float)c.w); }
            epart += ((xp.x * (-0.5f * y.x - b.x) + xp.y * (-0.5f * y.y - b.y)) +
                      (xp.z * (-0.5f * y.z - b.z) + xp.w * (-0.5f * y.w - b.w)));
            float4 s;
            s.x = sgnf(y.x + b.x); s.y = sgnf(y.y + b.y);
            s.z = sgnf(y.z + b.z); s.w = sgnf(y.w + b.w);
            xsw4[(i & 3) * 513 + (i >> 2)] = s;
            if (wr) ((char4*)xout)[i] = make_char4((signed char)s.x, (signed char)s.y,
                                                   (signed char)s.z, (signed char)s.w);
        }
    }

    // ---- energy reduction: identical deterministic order in every block ----
    float ew = epart;
    #pragma unroll
    for (int off = 1; off < 64; off <<= 1) ew += __shfl_xor(ew, off);
    if (lane == 0) esum[wave] = ew;
    __syncthreads();
    const float E = ((esum[0] + esum[1]) + (esum[2] + esum[3])) +
                    ((esum[4] + esum[5]) + (esum[6] + esum[7]));

    if (t >= 2 && fabsf(E - eacc[t - 2]) < EPS) {   // uniform across grid
        if (tid == 0 && blockIdx.x == 0) *done = 1 + ((t - 1) & 1);
        return;                              // final = x_{t-1}, frozen in xpk
    }
    if (t >= 1 && blockIdx.x == 0 && tid == 0) eacc[t - 1] = E;

    // ---- int8 screen dot (exact integers for t>=1 -> order-independent) ----
    float a0 = 0.f, a1 = 0.f, a2 = 0.f, a3 = 0.f;
    #pragma unroll
    for (int p = 0; p < 8; ++p) {
        const int j = (p << 6) + lane;
        const float4 q0 = xsw4[j];
        const float4 q1 = xsw4[513 + j];
        const float4 q2 = xsw4[1026 + j];
        const float4 q3 = xsw4[1539 + j];
        const uint4 w = wq[p];
        ACC_CHUNK(w, q0, q1, q2, q3, a0, a1, a2, a3)
    }
    float tot_q = (a0 + a1) + (a2 + a3);
    #pragma unroll
    for (int off = 1; off < 64; off <<= 1) tot_q += __shfl_xor(tot_q, off);
    // all lanes now hold tot_q -> wave-uniform branching below

    const float br  = bias[row];
    const int   sat = satflag[row];
    float yfin = tot_q * QINV;

    if (fabsf(yfin + br) < TAU_I8 || sat) {
        // ---- residual refine: 8KB Rq row ----
        const uint4* Rr = (const uint4*)(Rq + (size_t)row * N);
        float r0 = 0.f, r1 = 0.f, r2 = 0.f, r3 = 0.f;
        #pragma unroll
        for (int p = 0; p < 8; ++p) {
            const int j = (p << 6) + lane;
            const float4 q0 = xsw4[j];
            const float4 q1 = xsw4[513 + j];
            const float4 q2 = xsw4[1026 + j];
            const float4 q3 = xsw4[1539 + j];
            const uint4 w = Rr[j];
            ACC_CHUNK(w, q0, q1, q2, q3, r0, r1, r2, r3)
        }
        float tot_r = (r0 + r1) + (r2 + r3);
        #pragma unroll
        for (int off = 1; off < 64; off <<= 1) tot_r += __shfl_xor(tot_r, off);
        yfin = tot_q * QINV + tot_r * RINV;

        if (fabsf(yfin + br) < TAU_R || sat) {
            // ---- exact fp32, bitwise-identical to validated R3 order ----
            const float4* Wf = (const float4*)(W + (size_t)row * N);
            float b0 = 0.f, b1 = 0.f, b2 = 0.f, b3 = 0.f;
            #pragma unroll
            for (int p = 0; p < 8; ++p) {
                const int j = p * 256 + lane;
                #pragma unroll
                for (int c = 0; c < 4; ++c) {
                    const int idx = j + c * 64;
                    const float4 w = Wf[idx];
                    const float4 q = xsw4[(idx & 3) * 513 + (idx >> 2)]; // == R3 xs4[idx]
                    const float d = w.x * q.x + w.y * q.y + w.z * q.z + w.w * q.w;
                    if (c == 0) b0 += d; else if (c == 1) b1 += d;
                    else if (c == 2) b2 += d; else b3 += d;
                }
            }
            float tot = (b0 + b1) + (b2 + b3);
            #pragma unroll
            for (int off = 32; off > 0; off >>= 1) tot += __shfl_down(tot, off);
            yfin = tot;                      // valid on lane 0 (the writer)
        }
    }
    if (lane == 0) yout[row] = yfin;
}

// ---------------------------------------------------------------------------
// out: if done -> decode frozen xpk; else k=127 check (E_127 vs E_126),
// emit x_127 or x_128 = sign(y_127 + b). Single block, deterministic.
// ---------------------------------------------------------------------------
__global__ __launch_bounds__(512)
void out_kernel(const float* __restrict__ bias,
                const signed char* __restrict__ xpk0,
                const signed char* __restrict__ xpk1,
                const float* __restrict__ y127,     // yv[1]
                const float* __restrict__ eacc,
                const int* __restrict__ done,
                float* __restrict__ out) {
    __shared__ float red[512];
    const int tid = threadIdx.x;
    const int d = *done;
    float4* o4 = (float4*)out;

    if (d) {
        const char4* p4 = (const char4*)((d - 1) ? xpk1 : xpk0);
        for (int i = tid; i < N / 4; i += 512) {
            char4 c = p4[i];
            o4[i] = make_float4((float)c.x, (float)c.y, (float)c.z, (float)c.w);
        }
        return;
    }
    const char4*  xp4 = (const char4*)xpk1;      // x_127
    const float4* y4  = (const float4*)y127;
    const float4* b4  = (const float4*)bias;
    float ep = 0.f;
    for (int i = tid; i < N / 4; i += 512) {
        char4 c = xp4[i];
        float4 y = y4[i], b = b4[i];
        ep += (((float)c.x * (-0.5f * y.x - b.x) + (float)c.y * (-0.5f * y.y - b.y)) +
               ((float)c.z * (-0.5f * y.z - b.z) + (float)c.w * (-0.5f * y.w - b.w)));
    }
    red[tid] = ep;
    __syncthreads();
    #pragma unroll
    for (int s = 256; s > 0; s >>= 1) {
        if (tid < s) red[tid] += red[tid + s];
        __syncthreads();
    }
    const bool conv = fabsf(red[0] - eacc[126]) < EPS;  // k=127 check
    for (int i = tid; i < N / 4; i += 512) {
        char4 c = xp4[i];
        float4 y = y4[i], b = b4[i];
        float4 r;
        r.x = conv ? (float)c.x : sgnf(y.x + b.x);
        r.y = conv ? (float)c.y : sgnf(y.y + b.y);
        r.z = conv ? (float)c.z : sgnf(y.z + b.z);
        r.w = conv ? (float)c.w : sgnf(y.w + b.w);
        o4[i] = r;
    }
}

// ===========================================================================
// Fallback (ws too small): the validated R3 full-fp32 chain.
// ===========================================================================
__global__ __launch_bounds__(256) void fb_init(float* __restrict__ eacc,
                                               int* __restrict__ done) {
    int i = threadIdx.x;
    if (i <= MAX_ITER) eacc[i] = 0.0f;
    if (i == 0) *done = 0;
}

__global__ __launch_bounds__(512, 4) void fb_mv(const float* __restrict__ W,
                                                const float* __restrict__ bias,
                                                const float* __restrict__ x0,
                                                const signed char* __restrict__ xin,
                                                signed char* __restrict__ xnext,
                                                float* __restrict__ eacc,
                                                int t,
                                                int* __restrict__ done) {
    if (t >= 2) {
        if (*done) return;
        float d = fabsf(eacc[t - 1] - eacc[t - 2]);
        if (d < EPS) {
            if (threadIdx.x == 0) *done = 1 + ((t - 1) & 1);
            return;
        }
    }
    __shared__ float xs[N];
    __shared__ float wsum[8];
    if (t == 0) {
        const float4* x4 = (const float4*)x0;
        float4* s4 = (float4*)xs;
        for (int i = threadIdx.x; i < N / 4; i += 512) s4[i] = x4[i];
    } else {
        #pragma unroll
        for (int k = 0; k < 16; ++k) {
            int e = threadIdx.x + k * 512;
            xs[e] = (float)xin[e];
        }
    }
    __syncthreads();
    const int wave = threadIdx.x >> 6;
    const int lane = threadIdx.x & 63;
    const int row  = ((int)blockIdx.x << 3) + wave;
    const float4* Wr  = (const float4*)(W + (size_t)row * N);
    const float4* xs4 = (const float4*)xs;
    float a0 = 0.f, a1 = 0.f, a2 = 0.f, a3 = 0.f;
    #pragma unroll
    for (int p = 0; p < 8; ++p) {
        int j = p * 256 + lane;
        float4 w0 = Wr[j];         float4 q0 = xs4[j];
        float4 w1 = Wr[j + 64];    float4 q1 = xs4[j + 64];
        float4 w2 = Wr[j + 128];   float4 q2 = xs4[j + 128];
        float4 w3 = Wr[j + 192];   float4 q3 = xs4[j + 192];
        a0 += w0.x * q0.x + w0.y * q0.y + w0.z * q0.z + w0.w * q0.w;
        a1 += w1.x * q1.x + w1.y * q1.y + w1.z * q1.z + w1.w * q1.w;
        a2 += w2.x * q2.x + w2.y * q2.y + w2.z * q2.z + w2.w * q2.w;
        a3 += w3.x * q3.x + w3.y * q3.y + w3.z * q3.z + w3.w * q3.w;
    }
    float tot = (a0 + a1) + (a2 + a3);
    #pragma unroll
    for (int off = 32; off > 0; off >>= 1) tot += __shfl_down(tot, off);
    if (lane == 0) {
        float br = bias[row];
        float v = tot + br;
        xnext[row] = (signed char)((v > 0.f) ? 1 : ((v < 0.f) ? -1 : 0));
        float xr = xs[row];
        wsum[wave] = -0.5f * xr * tot - br * xr;
    }
    __syncthreads();
    if (threadIdx.x == 0) {
        float s = 0.f;
        #pragma unroll
        for (int w = 0; w < 8; ++w) s += wsum[w];
        atomicAdd(&eacc[t], s);
    }
}

__global__ __launch_bounds__(256) void fb_out(const signed char* __restrict__ p0,
                                              const signed char* __restrict__ p1,
                                              const int* __restrict__ done,
                                              float* __restrict__ out) {
    int i = blockIdx.x * 256 + threadIdx.x;
    int d = *done;
    const signed char* p = d ? ((d - 1) ? p1 : p0) : p0;
    out[i] = (float)p[i];
}

// ===========================================================================
extern "C" void kernel_launch(void* const* d_in, const int* in_sizes, int n_in,
                              void* d_out, int out_size, void* d_ws, size_t ws_size,
                              hipStream_t stream) {
    const float* x0 = (const float*)d_in[0];   // (8192,)
    const float* W  = (const float*)d_in[1];   // (8192, 8192) fp32
    const float* b  = (const float*)d_in[2];   // (8192,)
    float* out = (float*)d_out;

    // fast-path workspace layout
    char* p = (char*)d_ws;
    signed char* Wq = (signed char*)p;        p += (size_t)N * N;      // 64 MiB
    signed char* Rq = (signed char*)p;        p += (size_t)N * N;      // 64 MiB
    float* yv   = (float*)p;                  p += 2 * N * sizeof(float);
    signed char* xpk = (signed char*)p;       p += 2 * N;
    float* eacc = (float*)p;                  p += MAX_ITER * sizeof(float);
    int*   satflag = (int*)p;                 p += N * sizeof(int);
    int*   done = (int*)p;                    p += 16;
    const size_t needed = (size_t)(p - (char*)d_ws);

    if (ws_size >= needed) {
        init_kernel<<<N / 256, 256, 0, stream>>>(eacc, done, satflag);
        compress_kernel<<<(int)((size_t)N * N / (256 * 16)), 256, 0, stream>>>(W, Wq, Rq, satflag);
        for (int t = 0; t < MAX_ITER; ++t) {
            const float* yin = yv + ((t + 1) & 1) * N;          // y_{t-1}
            float*      yout = yv + (t & 1) * N;                // y_t
            const signed char* xprev = xpk + ((t + 1) & 1) * N; // x_{t-1}
            signed char*       xout  = xpk + (t & 1) * N;       // x_t
            step_kernel<<<N / 8, 512, 0, stream>>>(Wq, Rq, W, b, x0, yin, yout,
                                                   xprev, xout, eacc, satflag, t, done);
        }
        out_kernel<<<1, 512, 0, stream>>>(b, xpk, xpk + N, yv + N, eacc, done, out);
    } else {
        // fallback: validated R3 chain
        float*       feacc = (float*)d_ws;
        int*         fdone = (int*)(feacc + MAX_ITER + 2);
        signed char* p0    = (signed char*)(fdone + 16);
        signed char* p1    = p0 + N;
        fb_init<<<1, 256, 0, stream>>>(feacc, fdone);
        for (int t = 0; t <= MAX_ITER; ++t) {
            const signed char* xin   = (t & 1) ? p1 : p0;
            signed char*       xnext = (t & 1) ? p0 : p1;
            fb_mv<<<N / 8, 512, 0, stream>>>(W, b, x0, xin, xnext, feacc, t, fdone);
        }
        fb_out<<<N / 256, 256, 0, stream>>>(p0, p1, fdone, out);
    }
}

// Round 8
// 3344.702 us; speedup vs baseline: 1.5557x; 1.5557x over previous
//
#include <hip/hip_runtime.h>

#define N 8192
#define MAX_ITER 128
#define EPS 1e-6f
#define TAU_I8 12.0f     // int8 screen band: quant sigma ~1.63 -> 7.3 sigma
#define TAU_R  0.05f     // residual tier band: sigma ~6.4e-3 -> 7.8 sigma
#define QINV   0.0625f   // 1/16
#define RINV   (1.0f/4096.0f)
#define NPART  2048      // energy partial slots per parity

#if defined(__has_builtin)
#  if __has_builtin(__builtin_amdgcn_sdot4)
#    define SDOT4(a,b,c) __builtin_amdgcn_sdot4((a),(b),(c),false)
#  endif
#endif
#ifndef SDOT4
static __device__ __forceinline__ int sdot4_sw(int a, int b, int c) {
    c += (int)(signed char)(a & 0xff)       * (int)(signed char)(b & 0xff);
    c += (int)(signed char)((a>>8) & 0xff)  * (int)(signed char)((b>>8) & 0xff);
    c += (int)(signed char)((a>>16) & 0xff) * (int)(signed char)((b>>16) & 0xff);
    c += (int)(signed char)((a>>24) & 0xff) * (int)(signed char)((b>>24) & 0xff);
    return c;
}
#define SDOT4(a,b,c) sdot4_sw((a),(b),(c))
#endif

__device__ __forceinline__ float sgnf(float v) {
    return (v > 0.f) ? 1.f : ((v < 0.f) ? -1.f : 0.f);
}

// ---------------------------------------------------------------------------
__global__ __launch_bounds__(256) void init_kernel(float* __restrict__ eacc,
                                                   int* __restrict__ done,
                                                   int* __restrict__ satflag) {
    int i = blockIdx.x * 256 + threadIdx.x;
    if (i < N) satflag[i] = 0;
    if (i < MAX_ITER) eacc[i] = 0.f;
    if (i == 0) *done = 0;
}

// ---------------------------------------------------------------------------
// compress: W fp32 -> Wq int8 (scale 16) + Rq int8 residual (scale 4096).
// ---------------------------------------------------------------------------
__global__ __launch_bounds__(256) void compress_kernel(const float* __restrict__ W,
                                                       signed char* __restrict__ Wq,
                                                       signed char* __restrict__ Rq,
                                                       int* __restrict__ satflag) {
    const size_t base = ((size_t)blockIdx.x * 256 + threadIdx.x) * 16;
    const float4* w4 = (const float4*)(W + base);
    int sat = 0;
    uint4 oq, orr;
    unsigned* pq = (unsigned*)&oq;
    unsigned* pr = (unsigned*)&orr;
    #pragma unroll
    for (int v = 0; v < 4; ++v) {
        float4 w = w4[v];
        unsigned uq = 0, ur = 0;
        const float* e = (const float*)&w;
        #pragma unroll
        for (int k = 0; k < 4; ++k) {
            int q = __float2int_rn(e[k] * 16.0f);
            if (q > 127)  { q = 127;  sat = 1; }
            if (q < -127) { q = -127; sat = 1; }
            float r = e[k] - (float)q * QINV;        // exact (same binade)
            int rq = __float2int_rn(r * 4096.0f);
            if (rq > 127)  rq = 127;
            if (rq < -127) rq = -127;
            uq |= ((unsigned)(q & 0xff)) << (8 * k);
            ur |= ((unsigned)(rq & 0xff)) << (8 * k);
        }
        pq[v] = uq; pr[v] = ur;
    }
    *(uint4*)(Wq + base) = oq;
    *(uint4*)(Rq + base) = orr;
    if (sat) atomicOr(&satflag[base >> 13], 1);
}

// ---------------------------------------------------------------------------
// t0: exact fp32 matvec y0 = W@x0 (validated R3 accumulation order).
// Writes packed x_1 = sign(y0+b) and deterministic E_0 partials (zero-pads
// slots 1024..2047 so later 2048-slot reductions are well-defined).
// ---------------------------------------------------------------------------
__global__ __launch_bounds__(512, 4)
void t0_kernel(const float* __restrict__ W,
               const float* __restrict__ bias,
               const float* __restrict__ x0,
               signed char* __restrict__ xout,      // packed x_1
               float* __restrict__ pout) {          // partial[0], 2048 slots
    __shared__ float xs[N];
    __shared__ float esum[8];
    const int tid = threadIdx.x;
    {
        const float4* x4 = (const float4*)x0;
        float4* s4 = (float4*)xs;
        for (int i = tid; i < N / 4; i += 512) s4[i] = x4[i];
    }
    __syncthreads();
    const int wave = tid >> 6;
    const int lane = tid & 63;
    const int row  = ((int)blockIdx.x << 3) + wave;
    const float4* Wr  = (const float4*)(W + (size_t)row * N);
    const float4* xs4 = (const float4*)xs;
    float a0 = 0.f, a1 = 0.f, a2 = 0.f, a3 = 0.f;
    #pragma unroll
    for (int p = 0; p < 8; ++p) {                    // EXACT R3 inner body
        int j = p * 256 + lane;
        float4 w0 = Wr[j];         float4 q0 = xs4[j];
        float4 w1 = Wr[j + 64];    float4 q1 = xs4[j + 64];
        float4 w2 = Wr[j + 128];   float4 q2 = xs4[j + 128];
        float4 w3 = Wr[j + 192];   float4 q3 = xs4[j + 192];
        a0 += w0.x * q0.x + w0.y * q0.y + w0.z * q0.z + w0.w * q0.w;
        a1 += w1.x * q1.x + w1.y * q1.y + w1.z * q1.z + w1.w * q1.w;
        a2 += w2.x * q2.x + w2.y * q2.y + w2.z * q2.z + w2.w * q2.w;
        a3 += w3.x * q3.x + w3.y * q3.y + w3.z * q3.z + w3.w * q3.w;
    }
    float tot = (a0 + a1) + (a2 + a3);
    #pragma unroll
    for (int off = 32; off > 0; off >>= 1) tot += __shfl_down(tot, off);
    if (lane == 0) {
        const float br = bias[row];
        const float v = tot + br;
        xout[row] = (signed char)((v > 0.f) ? 1 : ((v < 0.f) ? -1 : 0));
        const float xr = xs[row];                    // real-valued x0
        esum[wave] = -0.5f * xr * tot - br * xr;
    }
    __syncthreads();
    if (tid == 0) {
        float s = ((esum[0] + esum[1]) + (esum[2] + esum[3])) +
                  ((esum[4] + esum[5]) + (esum[6] + esum[7]));
        pout[blockIdx.x] = s;
        pout[1024 + blockIdx.x] = 0.f;               // zero-pad upper half
    }
}

// ---------------------------------------------------------------------------
// step(t), t=1..127: 2048 blocks x 256 thr (4 waves, 1 row/wave),
// __launch_bounds__(256,8) -> 32 waves/CU for memory-level parallelism.
//   preload Wq row (8 uint4); stage packed x_t (8 KB) into LDS;
//   reduce 2048 E_{t-1} partials in fixed order (identical in every block);
//   uniform convergence check; sdot4 screen; Rq tier; exact-fp32 tier;
//   lane0 writes x_{t+1}[row] byte; block writes E_t partial.
// ---------------------------------------------------------------------------
__global__ __launch_bounds__(256, 8)
void step_kernel(const signed char* __restrict__ Wq,
                 const signed char* __restrict__ Rq,
                 const float* __restrict__ W,
                 const float* __restrict__ bias,
                 const unsigned* __restrict__ xin,    // packed x_t (2048 uints)
                 signed char* __restrict__ xout,      // packed x_{t+1}
                 const float* __restrict__ pin,       // E_{t-1} partials
                 float* __restrict__ pout,            // E_t partials
                 float* __restrict__ eacc,
                 const int* __restrict__ satflag,
                 int t,
                 int* __restrict__ done) {
    if (*done) return;                       // uniform

    __shared__ unsigned xq[2048];            // 8 KB packed x
    __shared__ float red[256];
    __shared__ float esum[4];

    const int tid  = threadIdx.x;
    const int wave = tid >> 6;
    const int lane = tid & 63;
    const int row  = ((int)blockIdx.x << 2) + wave;

    // preload int8 W row (loads overlap the stage/reduce phase)
    const uint4* Wr = (const uint4*)(Wq + (size_t)row * N);
    uint4 wq[8];
    #pragma unroll
    for (int p = 0; p < 8; ++p) wq[p] = Wr[(p << 6) + lane];

    // stage packed x_t
    {
        const uint4* xg4 = (const uint4*)xin;
        uint4* xs4w = (uint4*)xq;
        xs4w[tid]       = xg4[tid];
        xs4w[tid + 256] = xg4[tid + 256];
    }
    // deterministic fixed-order energy reduction (identical in all blocks)
    float s = 0.f;
    #pragma unroll
    for (int k = 0; k < 8; ++k) s += pin[(tid << 3) + k];
    red[tid] = s;
    __syncthreads();                         // also publishes xq
    #pragma unroll
    for (int off = 128; off > 0; off >>= 1) {
        if (tid < off) red[tid] += red[tid + off];
        __syncthreads();
    }
    const float E = red[0];                  // E_{t-1}

    if (t >= 2 && fabsf(E - eacc[t - 2]) < EPS) {
        if (blockIdx.x == 0 && tid == 0) *done = 1 + ((t - 1) & 1);
        return;                              // final = x_{t-1}, frozen
    }
    if (blockIdx.x == 0 && tid == 0) eacc[t - 1] = E;

    // ---- sdot4 screen: exact int32, order-independent ----
    const uint4* xs4 = (const uint4*)xq;
    int acc = 0;
    #pragma unroll
    for (int p = 0; p < 8; ++p) {
        const uint4 xv = xs4[(p << 6) + lane];
        const uint4 w  = wq[p];
        acc = SDOT4((int)w.x, (int)xv.x, acc);
        acc = SDOT4((int)w.y, (int)xv.y, acc);
        acc = SDOT4((int)w.z, (int)xv.z, acc);
        acc = SDOT4((int)w.w, (int)xv.w, acc);
    }
    #pragma unroll
    for (int off = 1; off < 64; off <<= 1) acc += __shfl_xor(acc, off);
    // all lanes hold acc -> wave-uniform tier branching

    const float br  = bias[row];             // wave-uniform broadcast load
    const int   sat = satflag[row];
    float yfin = (float)acc * QINV;

    if (fabsf(yfin + br) < TAU_I8 || sat) {
        // ---- residual tier: 8 KB Rq row, exact int32 ----
        const uint4* Rr = (const uint4*)(Rq + (size_t)row * N);
        int racc = 0;
        #pragma unroll
        for (int p = 0; p < 8; ++p) {
            const uint4 xv = xs4[(p << 6) + lane];
            const uint4 w  = Rr[(p << 6) + lane];
            racc = SDOT4((int)w.x, (int)xv.x, racc);
            racc = SDOT4((int)w.y, (int)xv.y, racc);
            racc = SDOT4((int)w.z, (int)xv.z, racc);
            racc = SDOT4((int)w.w, (int)xv.w, racc);
        }
        #pragma unroll
        for (int off = 1; off < 64; off <<= 1) racc += __shfl_xor(racc, off);
        yfin = (float)acc * QINV + (float)racc * RINV;

        if (fabsf(yfin + br) < TAU_R || sat) {
            // ---- exact fp32, bitwise-identical to validated R3 order ----
            const float4* Wf = (const float4*)(W + (size_t)row * N);
            float b0 = 0.f, b1 = 0.f, b2 = 0.f, b3 = 0.f;
            #pragma unroll
            for (int p = 0; p < 8; ++p) {
                const int j = p * 256 + lane;
                #pragma unroll
                for (int c = 0; c < 4; ++c) {
                    const int idx = j + c * 64;
                    const float4 w = Wf[idx];
                    const unsigned u = xq[idx];      // elements 4idx..4idx+3
                    float4 q;
                    q.x = (float)(signed char)(u & 0xff);
                    q.y = (float)(signed char)((u >> 8) & 0xff);
                    q.z = (float)(signed char)((u >> 16) & 0xff);
                    q.w = (float)(signed char)(u >> 24);
                    const float d = w.x * q.x + w.y * q.y + w.z * q.z + w.w * q.w;
                    if (c == 0) b0 += d; else if (c == 1) b1 += d;
                    else if (c == 2) b2 += d; else b3 += d;
                }
            }
            float tot = (b0 + b1) + (b2 + b3);
            #pragma unroll
            for (int off = 32; off > 0; off >>= 1) tot += __shfl_down(tot, off);
            yfin = tot;                      // valid on lane 0 (the writer)
        }
    }

    if (lane == 0) {
        const float v = yfin + br;
        xout[row] = (signed char)((v > 0.f) ? 1 : ((v < 0.f) ? -1 : 0));
        const float xr = (float)(signed char)((xq[row >> 2] >> ((row & 3) * 8)) & 0xff);
        esum[wave] = -0.5f * xr * yfin - br * xr;    // E_t row term
    }
    __syncthreads();
    if (tid == 0)
        pout[blockIdx.x] = (esum[0] + esum[1]) + (esum[2] + esum[3]);
}

// ---------------------------------------------------------------------------
// out: if done -> decode frozen buffer; else replicate the step reduction on
// partial[1] to get E_127, compare vs eacc[126], pick x_127 (xpk1) or x_128
// (xpk0, already written by step 127). 1 block x 256 (matches step order).
// ---------------------------------------------------------------------------
__global__ __launch_bounds__(256)
void out_kernel(const signed char* __restrict__ xpk0,
                const signed char* __restrict__ xpk1,
                const float* __restrict__ pin1,      // partial[1] (t=127)
                const float* __restrict__ eacc,
                const int* __restrict__ done,
                float* __restrict__ out) {
    __shared__ float red[256];
    const int tid = threadIdx.x;
    const int d = *done;
    float4* o4 = (float4*)out;

    const signed char* xf;
    if (d) {
        xf = (d - 1) ? xpk1 : xpk0;
    } else {
        float s = 0.f;
        #pragma unroll
        for (int k = 0; k < 8; ++k) s += pin1[(tid << 3) + k];
        red[tid] = s;
        __syncthreads();
        #pragma unroll
        for (int off = 128; off > 0; off >>= 1) {
            if (tid < off) red[tid] += red[tid + off];
            __syncthreads();
        }
        const bool conv = fabsf(red[0] - eacc[126]) < EPS;   // k=127 check
        xf = conv ? xpk1 : xpk0;             // x_127 : x_128
    }
    const char4* p4 = (const char4*)xf;
    for (int i = tid; i < N / 4; i += 256) {
        char4 c = p4[i];
        o4[i] = make_float4((float)c.x, (float)c.y, (float)c.z, (float)c.w);
    }
}

// ===========================================================================
// Fallback (ws too small): the validated R3 full-fp32 chain.
// ===========================================================================
__global__ __launch_bounds__(256) void fb_init(float* __restrict__ eacc,
                                               int* __restrict__ done) {
    int i = threadIdx.x;
    if (i <= MAX_ITER) eacc[i] = 0.0f;
    if (i == 0) *done = 0;
}

__global__ __launch_bounds__(512, 4) void fb_mv(const float* __restrict__ W,
                                                const float* __restrict__ bias,
                                                const float* __restrict__ x0,
                                                const signed char* __restrict__ xin,
                                                signed char* __restrict__ xnext,
                                                float* __restrict__ eacc,
                                                int t,
                                                int* __restrict__ done) {
    if (t >= 2) {
        if (*done) return;
        float d = fabsf(eacc[t - 1] - eacc[t - 2]);
        if (d < EPS) {
            if (threadIdx.x == 0) *done = 1 + ((t - 1) & 1);
            return;
        }
    }
    __shared__ float xs[N];
    __shared__ float wsum[8];
    if (t == 0) {
        const float4* x4 = (const float4*)x0;
        float4* s4 = (float4*)xs;
        for (int i = threadIdx.x; i < N / 4; i += 512) s4[i] = x4[i];
    } else {
        #pragma unroll
        for (int k = 0; k < 16; ++k) {
            int e = threadIdx.x + k * 512;
            xs[e] = (float)xin[e];
        }
    }
    __syncthreads();
    const int wave = threadIdx.x >> 6;
    const int lane = threadIdx.x & 63;
    const int row  = ((int)blockIdx.x << 3) + wave;
    const float4* Wr  = (const float4*)(W + (size_t)row * N);
    const float4* xs4 = (const float4*)xs;
    float a0 = 0.f, a1 = 0.f, a2 = 0.f, a3 = 0.f;
    #pragma unroll
    for (int p = 0; p < 8; ++p) {
        int j = p * 256 + lane;
        float4 w0 = Wr[j];         float4 q0 = xs4[j];
        float4 w1 = Wr[j + 64];    float4 q1 = xs4[j + 64];
        float4 w2 = Wr[j + 128];   float4 q2 = xs4[j + 128];
        float4 w3 = Wr[j + 192];   float4 q3 = xs4[j + 192];
        a0 += w0.x * q0.x + w0.y * q0.y + w0.z * q0.z + w0.w * q0.w;
        a1 += w1.x * q1.x + w1.y * q1.y + w1.z * q1.z + w1.w * q1.w;
        a2 += w2.x * q2.x + w2.y * q2.y + w2.z * q2.z + w2.w * q2.w;
        a3 += w3.x * q3.x + w3.y * q3.y + w3.z * q3.z + w3.w * q3.w;
    }
    float tot = (a0 + a1) + (a2 + a3);
    #pragma unroll
    for (int off = 32; off > 0; off >>= 1) tot += __shfl_down(tot, off);
    if (lane == 0) {
        float br = bias[row];
        float v = tot + br;
        xnext[row] = (signed char)((v > 0.f) ? 1 : ((v < 0.f) ? -1 : 0));
        float xr = xs[row];
        wsum[wave] = -0.5f * xr * tot - br * xr;
    }
    __syncthreads();
    if (threadIdx.x == 0) {
        float s = 0.f;
        #pragma unroll
        for (int w = 0; w < 8; ++w) s += wsum[w];
        atomicAdd(&eacc[t], s);
    }
}

__global__ __launch_bounds__(256) void fb_out(const signed char* __restrict__ p0,
                                              const signed char* __restrict__ p1,
                                              const int* __restrict__ done,
                                              float* __restrict__ out) {
    int i = blockIdx.x * 256 + threadIdx.x;
    int d = *done;
    const signed char* p = d ? ((d - 1) ? p1 : p0) : p0;
    out[i] = (float)p[i];
}

// ===========================================================================
extern "C" void kernel_launch(void* const* d_in, const int* in_sizes, int n_in,
                              void* d_out, int out_size, void* d_ws, size_t ws_size,
                              hipStream_t stream) {
    const float* x0 = (const float*)d_in[0];   // (8192,)
    const float* W  = (const float*)d_in[1];   // (8192, 8192) fp32
    const float* b  = (const float*)d_in[2];   // (8192,)
    float* out = (float*)d_out;

    // fast-path workspace layout (16B-aligned pieces)
    char* p = (char*)d_ws;
    signed char* Wq = (signed char*)p;        p += (size_t)N * N;      // 64 MiB
    signed char* Rq = (signed char*)p;        p += (size_t)N * N;      // 64 MiB
    signed char* xpk0 = (signed char*)p;      p += N;                  // packed x (even)
    signed char* xpk1 = (signed char*)p;      p += N;                  // packed x (odd)
    float* partial = (float*)p;               p += 2 * NPART * sizeof(float);
    float* eacc = (float*)p;                  p += MAX_ITER * sizeof(float);
    int*   satflag = (int*)p;                 p += N * sizeof(int);
    int*   done = (int*)p;                    p += 16;
    const size_t needed = (size_t)(p - (char*)d_ws);

    if (ws_size >= needed) {
        init_kernel<<<N / 256, 256, 0, stream>>>(eacc, done, satflag);
        compress_kernel<<<(int)((size_t)N * N / (256 * 16)), 256, 0, stream>>>(W, Wq, Rq, satflag);
        // t=0: exact fp32, writes x_1 -> xpk1, E_0 partials -> partial[0]
        t0_kernel<<<N / 8, 512, 0, stream>>>(W, b, x0, xpk1, partial);
        for (int t = 1; t < MAX_ITER; ++t) {
            const unsigned* xin  = (const unsigned*)((t & 1) ? xpk1 : xpk0); // x_t
            signed char*    xout = ((t + 1) & 1) ? xpk1 : xpk0;              // x_{t+1}
            const float*    pin  = partial + ((t - 1) & 1) * NPART;          // E_{t-1}
            float*          pout = partial + (t & 1) * NPART;                // E_t
            step_kernel<<<NPART, 256, 0, stream>>>(Wq, Rq, W, b, xin, xout,
                                                   pin, pout, eacc, satflag, t, done);
        }
        out_kernel<<<1, 256, 0, stream>>>(xpk0, xpk1, partial + NPART, eacc, done, out);
    } else {
        // fallback: validated R3 chain
        float*       feacc = (float*)d_ws;
        int*         fdone = (int*)(feacc + MAX_ITER + 2);
        signed char* p0    = (signed char*)(fdone + 16);
        signed char* p1    = p0 + N;
        fb_init<<<1, 256, 0, stream>>>(feacc, fdone);
        for (int t = 0; t <= MAX_ITER; ++t) {
            const signed char* xin   = (t & 1) ? p1 : p0;
            signed char*       xnext = (t & 1) ? p0 : p1;
            fb_mv<<<N / 8, 512, 0, stream>>>(W, b, x0, xin, xnext, feacc, t, fdone);
        }
        fb_out<<<N / 256, 256, 0, stream>>>(p0, p1, fdone, out);
    }
}